// Round 1
// baseline (253.467 us; speedup 1.0000x reference)
//
#include <hip/hip_runtime.h>
#include <math.h>

#define WHN 9216
#define PN 32
#define FN 128
#define BN 8
#define EPSF 1e-8f

// ws layout (floats):
//   wsM   : [8][32][32] at 0      (8192)   Gram  M = G_rr + G_ii   (raw, unnormalized)
//   wsA   : [8][32][32] at 8192   (8192)   Gram  A = X - X^T       (raw)
//   wsc   : [8][32]     at 16384  (256)    c_p = (1/P)/(norm_p + EPS)
//   wsinv : [8][128]    at 16640  (1024)   1/fnorm
//   wsbias: [8][128]    at 17664  (1024)   interpolated bias
// total 18688 floats = 74752 bytes

// ---------------- K1: Gram matrices ----------------
// grid (72, 8), block 256. Each block: 128 pixels of one batch.
__global__ __launch_bounds__(256) void k_gram(const float* __restrict__ ms,
                                              float* __restrict__ wsM,
                                              float* __restrict__ wsA) {
  const int b = blockIdx.y;
  const int chunk = blockIdx.x;            // 72 chunks * 128 px = 9216
  const int tid = threadIdx.x;
  __shared__ float4 sA[32][32];            // [x-quad][p ^ xq]  (swizzled)
  __shared__ float4 sB[32][32];
  __shared__ float pbuf[2][2048];
  const float4* ms4 = (const float4*)ms;
  // load 128 px * 32 p * 2 comps, coalesced, swizzled LDS store
#pragma unroll
  for (int k = 0; k < 4; ++k) {
    int i4 = tid + k * 256;
    int xq = i4 & 31, p = i4 >> 5;
    sA[xq][p ^ xq] = ms4[((b * 2 + 0) * 32 + p) * 2304 + chunk * 32 + xq];
    sB[xq][p ^ xq] = ms4[((b * 2 + 1) * 32 + p) * 2304 + chunk * 32 + xq];
  }
  __syncthreads();
  const int w = tid >> 6, lane = tid & 63;
  const int pg = lane & 7, qg = lane >> 3;   // lane -> 4x4 tile with stride-8 p,q
  float accM[4][4] = {{0}}, accA[4][4] = {{0}};
  for (int xq = w; xq < 32; xq += 4) {       // each wave: 8 pixel-quads
    float4 pa[4], pb[4], qa[4], qb[4];
#pragma unroll
    for (int j = 0; j < 4; ++j) {
      pa[j] = sA[xq][(pg + 8 * j) ^ xq];
      pb[j] = sB[xq][(pg + 8 * j) ^ xq];
      qa[j] = sA[xq][(qg + 8 * j) ^ xq];
      qb[j] = sB[xq][(qg + 8 * j) ^ xq];
    }
#pragma unroll
    for (int j = 0; j < 4; ++j)
#pragma unroll
      for (int k = 0; k < 4; ++k) {
        accM[j][k] += pa[j].x * qa[k].x + pb[j].x * qb[k].x
                    + pa[j].y * qa[k].y + pb[j].y * qb[k].y
                    + pa[j].z * qa[k].z + pb[j].z * qb[k].z
                    + pa[j].w * qa[k].w + pb[j].w * qb[k].w;
        accA[j][k] += pa[j].x * qb[k].x - pb[j].x * qa[k].x
                    + pa[j].y * qb[k].y - pb[j].y * qa[k].y
                    + pa[j].z * qb[k].z - pb[j].z * qa[k].z
                    + pa[j].w * qb[k].w - pb[j].w * qa[k].w;
      }
  }
  // cross-wave reduce in LDS, then one atomic per (mat,p,q) per block
  if (w < 2) {
#pragma unroll
    for (int j = 0; j < 4; ++j)
#pragma unroll
      for (int k = 0; k < 4; ++k) {
        pbuf[w][lane * 32 + j * 4 + k] = accM[j][k];
        pbuf[w][lane * 32 + 16 + j * 4 + k] = accA[j][k];
      }
  }
  __syncthreads();
  if (w >= 2) {
#pragma unroll
    for (int j = 0; j < 4; ++j)
#pragma unroll
      for (int k = 0; k < 4; ++k) {
        pbuf[w - 2][lane * 32 + j * 4 + k] += accM[j][k];
        pbuf[w - 2][lane * 32 + 16 + j * 4 + k] += accA[j][k];
      }
  }
  __syncthreads();
  for (int idx = tid; idx < 2048; idx += 256) {
    float v = pbuf[0][idx] + pbuf[1][idx];
    int lane2 = idx >> 5, r = idx & 31;
    int mat = r >> 4, rr = r & 15, j = rr >> 2, k = rr & 3;
    int p = (lane2 & 7) + 8 * j, q = (lane2 >> 3) + 8 * k;
    float* dst = mat ? wsA : wsM;
    atomicAdd(dst + (b << 10) + p * 32 + q, v);
  }
}

// ---------------- Kaux: c_p + aux scalar ----------------
// 1 block, 256 threads; thread = (b,p)
__global__ __launch_bounds__(256) void k_aux(const float* __restrict__ t,
                                             const float* __restrict__ wsM,
                                             float* __restrict__ wsc,
                                             float* __restrict__ out) {
  const int tid = threadIdx.x;
  const int b = tid >> 5, p = tid & 31;
  float mpp = wsM[(b << 10) + p * 33];           // M[b][p][p] = norm^2
  wsc[tid] = (1.0f / 32.0f) / (sqrtf(mpp) + EPSF);
  float acc = 0.f;
  for (int f = 0; f < FN; ++f) {
    float vr = t[((b * FN + f) * 2) * PN + p];
    float vi = t[((b * FN + f) * 2 + 1) * PN + p];
    acc = fmaf(vr, vr, acc);
    acc = fmaf(vi, vi, acc);
  }
  float val = logf(sqrtf(acc) + 1.0f);
  __shared__ float red[256];
  red[tid] = val;
  __syncthreads();
  for (int s = 128; s > 0; s >>= 1) {
    if (tid < s) red[tid] += red[tid + s];
    __syncthreads();
  }
  if (tid == 0) out[28311552] = red[0] * (1.0f / 256.0f);
}

// ---------------- K2: fnorm via Gram bilinear form + bias interp ----------------
// grid 1024 (= B*F), 64 threads (1 wave)
__global__ __launch_bounds__(64) void k_fnorm(const float* __restrict__ t,
                                              const float* __restrict__ freqs,
                                              const float* __restrict__ btab,
                                              const float* __restrict__ wsM,
                                              const float* __restrict__ wsA,
                                              const float* __restrict__ wsc,
                                              float* __restrict__ wsinv,
                                              float* __restrict__ wsbias) {
  const int bf = blockIdx.x;
  const int b = bf >> 7;
  const int lane = threadIdx.x;
  __shared__ float tt[64];                 // [0:32)=a_p*c_p, [32:64)=b_p*c_p
  {
    int p = lane & 31, comp = lane >> 5;
    tt[lane] = t[(bf * 2 + comp) * PN + p] * wsc[(b << 5) + p];
  }
  __syncthreads();
  const int pp = lane & 31, qh = lane >> 5;     // lane: row pp, q-halve qh
  const float* Mrow = wsM + (b << 10) + pp * 32 + qh * 16;
  const float* Arow = wsA + (b << 10) + pp * 32 + qh * 16;
  float ap = tt[pp], bp = tt[32 + pp];
  float S = 0.f;
#pragma unroll
  for (int k = 0; k < 16; ++k) {
    int q = qh * 16 + k;
    float aq = tt[q], bq = tt[32 + q];
    S += (ap * aq + bp * bq) * Mrow[k] + 2.0f * (bp * aq) * Arow[k];
  }
#pragma unroll
  for (int off = 32; off; off >>= 1) S += __shfl_xor(S, off);
  if (lane == 0) {
    float fn = sqrtf(fmaxf(S, 1.1920929e-7f));  // FLT_EPSILON clip
    wsinv[bf] = 1.0f / fn;
    float x = freqs[bf];
    float idx = (x + 1.0f) * 0.5f * 249.0f;
    idx = fminf(fmaxf(idx, 0.0f), 249.0f);
    float fi = floorf(idx);
    int i0 = (int)fi;
    int i1 = min(i0 + 1, 249);
    float wv = idx - fi;
    wsbias[bf] = btab[i0] * (1.0f - wv) + btab[i1] * wv;
  }
}

// ---------------- K3: main fused pass ----------------
// grid (36, 8, 2), block 256. thread = pixel; z splits f-range for occupancy.
__global__ __launch_bounds__(256) void k_main(const float* __restrict__ ms,
                                              const float* __restrict__ t,
                                              const float* __restrict__ wsc,
                                              const float* __restrict__ wsinv,
                                              const float* __restrict__ wsbias,
                                              float* __restrict__ out) {
  const int b = blockIdx.y;
  const int pix = blockIdx.x * 256 + threadIdx.x;
  const int f0 = blockIdx.z * 64;
  float csr[32], csi[32];
  const float* msb = ms + (b * 64) * WHN + pix;
#pragma unroll
  for (int p = 0; p < 32; ++p) {
    float c = wsc[(b << 5) + p];
    csr[p] = msb[p * WHN] * c;
    csi[p] = msb[(32 + p) * WHN] * c;
  }
  const int LNOFF = BN * FN * WHN;  // 9437184
#pragma unroll 2
  for (int f = f0; f < f0 + 64; ++f) {
    const float* tp = t + ((b * FN + f) * 2) * PN;  // wave-uniform -> s_load
    float ra = 0.f, rb = 0.f, ia = 0.f, ib = 0.f;
#pragma unroll
    for (int p = 0; p < 32; ++p) {
      float a = tp[p], bb = tp[32 + p];
      ra = fmaf(csr[p], a, ra);   // rr
      rb = fmaf(csi[p], bb, rb);  // ii
      ia = fmaf(csr[p], bb, ia);  // ri
      ib = fmaf(csi[p], a, ib);   // ir
    }
    float r = ra - rb, im = ia + ib;
    float mag2 = fmaf(r, r, im * im);
    int fo = b * FN + f;
    float lm = (__logf(mag2 + EPSF) + wsbias[fo]) * (1.0f / 4.2f);
    float inv = wsinv[fo];
    out[fo * WHN + pix] = lm;
    out[LNOFF + (fo * 2) * WHN + pix] = r * inv;
    out[LNOFF + (fo * 2 + 1) * WHN + pix] = im * inv;
  }
}

extern "C" void kernel_launch(void* const* d_in, const int* in_sizes, int n_in,
                              void* d_out, int out_size, void* d_ws, size_t ws_size,
                              hipStream_t stream) {
  const float* ms = (const float*)d_in[0];   // mode_shapes  (8,2,32,96,96)
  const float* t  = (const float*)d_in[1];   // mode_responses (8,128,2,32)
  const float* fr = (const float*)d_in[2];   // freqs (8,128)
  const float* bt = (const float*)d_in[3];   // bias_table (250,)
  float* out = (float*)d_out;
  float* ws = (float*)d_ws;
  float* wsM = ws;
  float* wsA = ws + 8192;
  float* wsc = ws + 16384;
  float* wsinv = ws + 16640;
  float* wsbias = ws + 17664;

  hipMemsetAsync(ws, 0, 16384 * sizeof(float), stream);  // zero M, A
  hipLaunchKernelGGL(k_gram, dim3(72, 8), dim3(256), 0, stream, ms, wsM, wsA);
  hipLaunchKernelGGL(k_aux, dim3(1), dim3(256), 0, stream, t, wsM, wsc, out);
  hipLaunchKernelGGL(k_fnorm, dim3(1024), dim3(64), 0, stream, t, fr, bt, wsM, wsA, wsc, wsinv, wsbias);
  hipLaunchKernelGGL(k_main, dim3(36, 8, 2), dim3(256), 0, stream, ms, t, wsc, wsinv, wsbias, out);
}

// Round 2
// 168.903 us; speedup vs baseline: 1.5007x; 1.5007x over previous
//
#include <hip/hip_runtime.h>
#include <math.h>

#define WHN 9216
#define PN 32
#define FN 128
#define BN 8
#define EPSF 1e-8f
#define INV_STD 0.23809523809f   // 1/4.2
#define AUX_IDX 28311552         // 8*128*9216 + 8*128*2*9216

typedef __attribute__((ext_vector_type(8))) short short8;
typedef __attribute__((ext_vector_type(16))) float f32x16;

__device__ __forceinline__ unsigned short f2bf(float x) {
  unsigned int u = __float_as_uint(x);
  unsigned int r = (u + 0x7FFFu + ((u >> 16) & 1u)) >> 16;  // RNE
  return (unsigned short)r;
}
__device__ __forceinline__ float bf2f(unsigned short h) {
  return __uint_as_float(((unsigned int)h) << 16);
}

// ---------------- K1: Gram partials (or atomic fallback) ----------------
// grid (72, 8), block 256. Each block: 128 pixels of one batch.
__global__ __launch_bounds__(256) void k_gram(const float* __restrict__ ms,
                                              float* __restrict__ wsM,
                                              float* __restrict__ wsA,
                                              float* __restrict__ part,
                                              int use_part) {
  const int b = blockIdx.y;
  const int chunk = blockIdx.x;
  const int tid = threadIdx.x;
  __shared__ float4 sA[32][32];
  __shared__ float4 sB[32][32];
  __shared__ float pbuf[2][2048];
  const float4* ms4 = (const float4*)ms;
#pragma unroll
  for (int k = 0; k < 4; ++k) {
    int i4 = tid + k * 256;
    int xq = i4 & 31, p = i4 >> 5;
    sA[xq][p ^ xq] = ms4[((b * 2 + 0) * 32 + p) * 2304 + chunk * 32 + xq];
    sB[xq][p ^ xq] = ms4[((b * 2 + 1) * 32 + p) * 2304 + chunk * 32 + xq];
  }
  __syncthreads();
  const int w = tid >> 6, lane = tid & 63;
  const int pg = lane & 7, qg = lane >> 3;
  float accM[4][4] = {{0}}, accA[4][4] = {{0}};
  for (int xq = w; xq < 32; xq += 4) {
    float4 pa[4], pb[4], qa[4], qb[4];
#pragma unroll
    for (int j = 0; j < 4; ++j) {
      pa[j] = sA[xq][(pg + 8 * j) ^ xq];
      pb[j] = sB[xq][(pg + 8 * j) ^ xq];
      qa[j] = sA[xq][(qg + 8 * j) ^ xq];
      qb[j] = sB[xq][(qg + 8 * j) ^ xq];
    }
#pragma unroll
    for (int j = 0; j < 4; ++j)
#pragma unroll
      for (int k = 0; k < 4; ++k) {
        accM[j][k] += pa[j].x * qa[k].x + pb[j].x * qb[k].x
                    + pa[j].y * qa[k].y + pb[j].y * qb[k].y
                    + pa[j].z * qa[k].z + pb[j].z * qb[k].z
                    + pa[j].w * qa[k].w + pb[j].w * qb[k].w;
        accA[j][k] += pa[j].x * qb[k].x - pb[j].x * qa[k].x
                    + pa[j].y * qb[k].y - pb[j].y * qa[k].y
                    + pa[j].z * qb[k].z - pb[j].z * qa[k].z
                    + pa[j].w * qb[k].w - pb[j].w * qa[k].w;
      }
  }
  if (w < 2) {
#pragma unroll
    for (int j = 0; j < 4; ++j)
#pragma unroll
      for (int k = 0; k < 4; ++k) {
        pbuf[w][lane * 32 + j * 4 + k] = accM[j][k];
        pbuf[w][lane * 32 + 16 + j * 4 + k] = accA[j][k];
      }
  }
  __syncthreads();
  if (w >= 2) {
#pragma unroll
    for (int j = 0; j < 4; ++j)
#pragma unroll
      for (int k = 0; k < 4; ++k) {
        pbuf[w - 2][lane * 32 + j * 4 + k] += accM[j][k];
        pbuf[w - 2][lane * 32 + 16 + j * 4 + k] += accA[j][k];
      }
  }
  __syncthreads();
  for (int idx = tid; idx < 2048; idx += 256) {
    float v = pbuf[0][idx] + pbuf[1][idx];
    if (use_part) {
      part[((size_t)(b * 72 + chunk)) * 2048 + idx] = v;
    } else {
      int lane2 = idx >> 5, r = idx & 31;
      int mat = r >> 4, rr = r & 15, j = rr >> 2, k = rr & 3;
      int p = (lane2 & 7) + 8 * j, q = (lane2 >> 3) + 8 * k;
      float* dst = mat ? wsA : wsM;
      atomicAdd(dst + (b << 10) + p * 32 + q, v);
    }
  }
}

// ---------------- K1b: reduce partials -> M, A, c ----------------
// grid 64, block 256 (16384 threads = 8 b * 2048 slots)
__global__ __launch_bounds__(256) void k_reduce(const float* __restrict__ part,
                                                float* __restrict__ wsM,
                                                float* __restrict__ wsA,
                                                float* __restrict__ wsc) {
  int g = blockIdx.x * 256 + threadIdx.x;
  int b = g >> 11, idx = g & 2047;
  const float* p = part + ((size_t)b * 72) * 2048 + idx;
  float s = 0.f;
#pragma unroll 8
  for (int c = 0; c < 72; ++c) s += p[(size_t)c * 2048];
  int lane2 = idx >> 5, r = idx & 31;
  int mat = r >> 4, rr = r & 15, j = rr >> 2, k = rr & 3;
  int pp = (lane2 & 7) + 8 * j, q = (lane2 >> 3) + 8 * k;
  (mat ? wsA : wsM)[(b << 10) + pp * 32 + q] = s;
  if (!mat && pp == q) wsc[(b << 5) + pp] = (1.0f / 32.0f) / (sqrtf(s) + EPSF);
}

// ---------------- c from M diag (atomic fallback path only) ----------------
__global__ void k_cfromM(const float* __restrict__ wsM, float* __restrict__ wsc) {
  int tid = threadIdx.x;
  int b = tid >> 5, p = tid & 31;
  float m = wsM[(b << 10) + p * 33];
  wsc[tid] = (1.0f / 32.0f) / (sqrtf(m) + EPSF);
}

// ---------------- K_aux: aux_sparse scalar ----------------
// grid 8 (b), block 256; float4-coalesced; atomicAdd into memset-zeroed slot
__global__ __launch_bounds__(256) void k_aux(const float* __restrict__ t,
                                             float* __restrict__ out) {
  const int b = blockIdx.x, tid = threadIdx.x;
  const float4* t4 = (const float4*)t + (size_t)b * 2048;
  float4 a; a.x = a.y = a.z = a.w = 0.f;
#pragma unroll
  for (int j = 0; j < 8; ++j) {
    float4 v = t4[tid + j * 256];
    a.x = fmaf(v.x, v.x, a.x);
    a.y = fmaf(v.y, v.y, a.y);
    a.z = fmaf(v.z, v.z, a.z);
    a.w = fmaf(v.w, v.w, a.w);
  }
#pragma unroll
  for (int off = 8; off <= 32; off <<= 1) {
    a.x += __shfl_xor(a.x, off);
    a.y += __shfl_xor(a.y, off);
    a.z += __shfl_xor(a.z, off);
    a.w += __shfl_xor(a.w, off);
  }
  __shared__ float sred[4][8][4];
  int wv = tid >> 6, lane = tid & 63;
  if (lane < 8) {
    sred[wv][lane][0] = a.x; sred[wv][lane][1] = a.y;
    sred[wv][lane][2] = a.z; sred[wv][lane][3] = a.w;
  }
  __syncthreads();
  if (tid < 8) {
    float s0 = 0, s1 = 0, s2 = 0, s3 = 0;
#pragma unroll
    for (int w2 = 0; w2 < 4; ++w2) {
      s0 += sred[w2][tid][0]; s1 += sred[w2][tid][1];
      s2 += sred[w2][tid][2]; s3 += sred[w2][tid][3];
    }
    float val = logf(sqrtf(s0) + 1.f) + logf(sqrtf(s1) + 1.f)
              + logf(sqrtf(s2) + 1.f) + logf(sqrtf(s3) + 1.f);
    val += __shfl_xor(val, 1);
    val += __shfl_xor(val, 2);
    val += __shfl_xor(val, 4);
    if (tid == 0) atomicAdd(out + AUX_IDX, val * (1.0f / 256.0f));
  }
}

// ---------------- K2: fnorm via Gram bilinear form + bias interp ----------------
__global__ __launch_bounds__(64) void k_fnorm(const float* __restrict__ t,
                                              const float* __restrict__ freqs,
                                              const float* __restrict__ btab,
                                              const float* __restrict__ wsM,
                                              const float* __restrict__ wsA,
                                              const float* __restrict__ wsc,
                                              float* __restrict__ wsinv,
                                              float* __restrict__ wsbias) {
  const int bf = blockIdx.x;
  const int b = bf >> 7;
  const int lane = threadIdx.x;
  __shared__ float tt[64];
  {
    int p = lane & 31, comp = lane >> 5;
    tt[lane] = t[(bf * 2 + comp) * PN + p] * wsc[(b << 5) + p];
  }
  __syncthreads();
  const int pp = lane & 31, qh = lane >> 5;
  const float* Mrow = wsM + (b << 10) + pp * 32 + qh * 16;
  const float* Arow = wsA + (b << 10) + pp * 32 + qh * 16;
  float ap = tt[pp], bp = tt[32 + pp];
  float S = 0.f;
#pragma unroll
  for (int k = 0; k < 16; ++k) {
    int q = qh * 16 + k;
    float aq = tt[q], bq = tt[32 + q];
    S += (ap * aq + bp * bq) * Mrow[k] + 2.0f * (bp * aq) * Arow[k];
  }
#pragma unroll
  for (int off = 32; off; off >>= 1) S += __shfl_xor(S, off);
  if (lane == 0) {
    float fn = sqrtf(fmaxf(S, 1.1920929e-7f));
    wsinv[bf] = 1.0f / fn;
    float x = freqs[bf];
    float idx = (x + 1.0f) * 0.5f * 249.0f;
    idx = fminf(fmaxf(idx, 0.0f), 249.0f);
    float fi = floorf(idx);
    int i0 = (int)fi;
    int i1 = min(i0 + 1, 249);
    float wvv = idx - fi;
    wsbias[bf] = btab[i0] * (1.0f - wvv) + btab[i1] * wvv;
  }
}

// ---------------- K3: main fused pass (split-bf16 MFMA) ----------------
// grid (72, 8), block 256 = 4 waves; wave w owns 32-px strip, all 128 f.
#define MFMA32(A, B, C) __builtin_amdgcn_mfma_f32_32x32x16_bf16(A, B, C, 0, 0, 0)
__global__ __launch_bounds__(256) void k_main(const float* __restrict__ ms,
                                              const float* __restrict__ t,
                                              const float* __restrict__ wsc,
                                              const float* __restrict__ wsinv,
                                              const float* __restrict__ wsbias,
                                              float* __restrict__ out) {
  __shared__ short tHs[8192];   // T2 hi, [128 f][64 k], k-group XOR-swizzled
  __shared__ short tLs[8192];   // T2 lo
  __shared__ float sInv[128], sBias[128], sC[32];
  const int b = blockIdx.y;
  const int tid = threadIdx.x;
  const int lane = tid & 63, wv = tid >> 6;
  const int col = lane & 31, hf = lane >> 5;
  const int pix = blockIdx.x * 128 + wv * 32 + col;

  // ---- S fragments: raw mode shapes, bf16 hi/lo split (global, no LDS) ----
  short8 sHf[4], sLf[4];
#pragma unroll
  for (int kg = 0; kg < 4; ++kg) {
#pragma unroll
    for (int j = 0; j < 8; ++j) {
      int k = kg * 16 + hf * 8 + j;
      float v = ms[(((size_t)b * 2 + (k >> 5)) * 32 + (k & 31)) * WHN + pix];
      unsigned short h = f2bf(v);
      sHf[kg][j] = (short)h;
      sLf[kg][j] = (short)f2bf(v - bf2f(h));
    }
  }
  short8 msk;
#pragma unroll
  for (int j = 0; j < 8; ++j) msk[j] = (short)0x8000;
  short8 nH2 = sHf[2] ^ msk, nL2 = sLf[2] ^ msk;
  short8 nH3 = sHf[3] ^ msk, nL3 = sLf[3] ^ msk;

  // ---- stage inv/bias/c ----
  if (tid < 128) sInv[tid] = wsinv[b * 128 + tid];
  else sBias[tid - 128] = wsbias[b * 128 + (tid - 128)];
  if (tid < 32) sC[tid] = wsc[b * 32 + tid];
  __syncthreads();

  // ---- stage T2 = c_p * [t_r ; t_i], hi/lo split, swizzled ----
#pragma unroll
  for (int it = 0; it < 4; ++it) {
    int gidx = tid + it * 256;          // (f, k-group)
    int f = gidx >> 3, g = gidx & 7;
    const float* src = t + ((size_t)(b * 128 + f) * 2 + (g >> 2)) * 32 + (g & 3) * 8;
    int gs = g ^ (f & 7);
    short8 hv, lv;
#pragma unroll
    for (int e = 0; e < 8; ++e) {
      float v = src[e] * sC[(g & 3) * 8 + e];
      unsigned short h = f2bf(v);
      hv[e] = (short)h;
      lv[e] = (short)f2bf(v - bf2f(h));
    }
    *(short8*)&tHs[f * 64 + gs * 8] = hv;
    *(short8*)&tLs[f * 64 + gs * 8] = lv;
  }
  __syncthreads();

  float* outF = out + (size_t)BN * FN * WHN;  // normed_field base

  for (int ft = 0; ft < 4; ++ft) {
    // A-fragments from LDS (row f = ft*32 + col)
    short8 tHf[4], tLf[4];
    int f = ft * 32 + col;
    int fx = f & 7;
#pragma unroll
    for (int kg = 0; kg < 4; ++kg) {
      int gs = (2 * kg + hf) ^ fx;
      tHf[kg] = *(const short8*)&tHs[f * 64 + gs * 8];
      tLf[kg] = *(const short8*)&tLs[f * 64 + gs * 8];
    }
    f32x16 aR, aI;
#pragma unroll
    for (int i = 0; i < 16; ++i) { aR[i] = 0.f; aI[i] = 0.f; }
    // R = t_r*csr (kg0,1) + t_i*(-csi) (kg2,3), 3-term split each
    aR = MFMA32(tHf[0], sHf[0], aR); aR = MFMA32(tHf[0], sLf[0], aR); aR = MFMA32(tLf[0], sHf[0], aR);
    aR = MFMA32(tHf[1], sHf[1], aR); aR = MFMA32(tHf[1], sLf[1], aR); aR = MFMA32(tLf[1], sHf[1], aR);
    aR = MFMA32(tHf[2], nH2,    aR); aR = MFMA32(tHf[2], nL2,    aR); aR = MFMA32(tLf[2], nH2,    aR);
    aR = MFMA32(tHf[3], nH3,    aR); aR = MFMA32(tHf[3], nL3,    aR); aR = MFMA32(tLf[3], nH3,    aR);
    // I = t_r*csi (pair with k-swapped S) + t_i*csr
    aI = MFMA32(tHf[0], sHf[2], aI); aI = MFMA32(tHf[0], sLf[2], aI); aI = MFMA32(tLf[0], sHf[2], aI);
    aI = MFMA32(tHf[1], sHf[3], aI); aI = MFMA32(tHf[1], sLf[3], aI); aI = MFMA32(tLf[1], sHf[3], aI);
    aI = MFMA32(tHf[2], sHf[0], aI); aI = MFMA32(tHf[2], sLf[0], aI); aI = MFMA32(tLf[2], sHf[0], aI);
    aI = MFMA32(tHf[3], sHf[1], aI); aI = MFMA32(tHf[3], sLf[1], aI); aI = MFMA32(tLf[3], sHf[1], aI);
    // epilogue: D col=lane&31 (pix), row=(reg&3)+8*(reg>>2)+4*(lane>>5)
#pragma unroll
    for (int r = 0; r < 16; ++r) {
      int row = (r & 3) + 8 * (r >> 2) + 4 * hf;
      int fo = ft * 32 + row;
      float vr = aR[r], vi = aI[r];
      float mag2 = fmaf(vr, vr, vi * vi);
      float ln = (__logf(mag2 + EPSF) + sBias[fo]) * INV_STD;
      float inv = sInv[fo];
      size_t fg = (size_t)(b * 128 + fo);
      out[fg * WHN + pix] = ln;
      outF[(fg * 2) * WHN + pix] = vr * inv;
      outF[(fg * 2 + 1) * WHN + pix] = vi * inv;
    }
  }
}

extern "C" void kernel_launch(void* const* d_in, const int* in_sizes, int n_in,
                              void* d_out, int out_size, void* d_ws, size_t ws_size,
                              hipStream_t stream) {
  const float* ms = (const float*)d_in[0];
  const float* t  = (const float*)d_in[1];
  const float* fr = (const float*)d_in[2];
  const float* bt = (const float*)d_in[3];
  float* out = (float*)d_out;
  float* ws = (float*)d_ws;
  float* wsM = ws;
  float* wsA = ws + 8192;
  float* wsc = ws + 16384;
  float* wsinv = ws + 16640;
  float* wsbias = ws + 17664;
  float* part = ws + 18688;
  size_t need = ((size_t)18688 + (size_t)576 * 2048) * 4;
  int use_part = (ws_size >= need) ? 1 : 0;

  hipMemsetAsync((char*)d_out + (size_t)AUX_IDX * 4, 0, 4, stream);
  if (use_part) {
    hipLaunchKernelGGL(k_gram, dim3(72, 8), dim3(256), 0, stream, ms, wsM, wsA, part, 1);
    hipLaunchKernelGGL(k_reduce, dim3(64), dim3(256), 0, stream, part, wsM, wsA, wsc);
  } else {
    hipMemsetAsync(ws, 0, 16384 * sizeof(float), stream);
    hipLaunchKernelGGL(k_gram, dim3(72, 8), dim3(256), 0, stream, ms, wsM, wsA, part, 0);
    hipLaunchKernelGGL(k_cfromM, dim3(1), dim3(256), 0, stream, wsM, wsc);
  }
  hipLaunchKernelGGL(k_fnorm, dim3(1024), dim3(64), 0, stream, t, fr, bt, wsM, wsA, wsc, wsinv, wsbias);
  hipLaunchKernelGGL(k_aux, dim3(8), dim3(256), 0, stream, t, out);
  hipLaunchKernelGGL(k_main, dim3(72, 8), dim3(256), 0, stream, ms, t, wsc, wsinv, wsbias, out);
}